// Round 1
// 6254.934 us; speedup vs baseline: 2.2582x; 2.2582x over previous
//
#include <hip/hip_runtime.h>
#include <cmath>

// Problem constants (B=1024 batches, S=200 nodes, E=128, H=8 heads, dh=16)
constexpr int Bn = 1024, Sn = 200, En = 128, Hn = 8, DHn = 16, Tn = 199;
constexpr long long LOGITS_N = (long long)Bn * Tn * Sn;   // 40,755,200
constexpr long long LOGP_OFF = LOGITS_N;                  // [B] log probs
constexpr long long SOL_OFF  = LOGP_OFF + Bn;             // [B][S] solution (as float)

#define NEG_INF (-__builtin_inff())

__device__ __forceinline__ float dot4(float4 a, float4 b) {
  return a.x * b.x + a.y * b.y + a.z * b.z + a.w * b.w;
}

// ---------------------------------------------------------------------------
// Kernel 1: per-batch query constants.
//   qtop[b] = mean_s(enc[b]) @ Wq_top
//   qh0[b]  = qtop[b] + vl@Wq_mid + vf@Wq_bot     (the full q at t=0)
// ---------------------------------------------------------------------------
__global__ __launch_bounds__(128) void hhat_kernel(
    const float* __restrict__ enc, const float* __restrict__ vl, const float* __restrict__ vf,
    const float* __restrict__ Wq, float* __restrict__ qtop, float* __restrict__ qh0)
{
  const int b = blockIdx.x, e = threadIdx.x;
  const float* p = enc + (size_t)b * Sn * En + e;
  float s = 0.f;
  for (int i = 0; i < Sn; ++i) s += p[(size_t)i * En];
  __shared__ float hl[En];
  hl[e] = s * (1.0f / Sn);
  __syncthreads();
  float qt = 0.f, qm = 0.f, qf = 0.f;
#pragma unroll 8
  for (int i = 0; i < En; ++i) {
    qt += hl[i] * Wq[i * En + e];
    qm += vl[i] * Wq[(En + i) * En + e];
    qf += vf[i] * Wq[(2 * En + i) * En + e];
  }
  qtop[(size_t)b * En + e] = qt;
  qh0[(size_t)b * En + e]  = qt + qm + qf;
}

// ---------------------------------------------------------------------------
// Kernel 2: projections (4 matmuls). 32 rows of enc per block.
//   Kall[b][s][e] = enc@Wk   (row-major, decode loads head-slices to regs)
//   Vall[b][s][e] = enc@Wv
//   QM  [b][s][e] = enc@Wq_mid   (hoists the per-step last@Wq_mid matmul)
//   KP2 [b][e>>2][s][e&3] = enc@Wp  (e-grouped-by-4 so decode's per-s
//                                    ds_read_b128 over LDS is dense)
// ---------------------------------------------------------------------------
__global__ __launch_bounds__(256) void proj_kernel(
    const float* __restrict__ enc,
    const float* __restrict__ Wk, const float* __restrict__ Wv,
    const float* __restrict__ Wq, const float* __restrict__ Wp,
    float* __restrict__ Kall, float* __restrict__ Vall,
    float* __restrict__ QM, float* __restrict__ KP2)
{
  __shared__ float et[32 * En];     // 16 KB tile of enc rows
  __shared__ float wl[En * En];     // 64 KB weight matrix (LDS-cached)
  const int tid = threadIdx.x;
  const size_t r0 = (size_t)blockIdx.x * 32;

  for (int i = tid; i < 32 * En; i += 256) et[i] = enc[r0 * En + i];

  const float* Ws[4] = {Wk, Wv, Wq + (size_t)En * En, Wp};
  float* Os[3] = {Kall, Vall, QM};
  for (int m = 0; m < 4; ++m) {
    __syncthreads();                       // protect wl before overwrite (and et after load)
    const float* W = Ws[m];
    for (int i = tid; i < En * En; i += 256) wl[i] = W[i];
    __syncthreads();
    const int j = tid & 127, half = tid >> 7;
    for (int rr = 0; rr < 16; ++rr) {
      const int r = rr * 2 + half;
      float a0 = 0.f, a1 = 0.f, a2 = 0.f, a3 = 0.f;
#pragma unroll 8
      for (int e = 0; e < En; e += 4) {
        a0 += et[r * En + e    ] * wl[(e    ) * En + j];
        a1 += et[r * En + e + 1] * wl[(e + 1) * En + j];
        a2 += et[r * En + e + 2] * wl[(e + 2) * En + j];
        a3 += et[r * En + e + 3] * wl[(e + 3) * En + j];
      }
      const float a = (a0 + a1) + (a2 + a3);
      const size_t rg = r0 + r;
      if (m < 3) {
        Os[m][rg * En + j] = a;
      } else {
        const int b = (int)(rg / Sn), s = (int)(rg - (size_t)b * Sn);
        KP2[(((size_t)b * 32 + (j >> 2)) * Sn + s) * 4 + (j & 3)] = a;
      }
    }
  }
}

// ---------------------------------------------------------------------------
// Kernel 3: sequential decode, one 512-thread block per batch, 199 steps.
// All per-step state is on-chip: K/V fragments in registers (wave = head),
// k_ptr in LDS, Wo in registers. Per-step global traffic = one 512 B QM row.
// ---------------------------------------------------------------------------
__global__ __launch_bounds__(512, 2) void decode_kernel(
    const float* __restrict__ enc, const float* __restrict__ Wq, const float* __restrict__ Wo,
    const float* __restrict__ Kall, const float* __restrict__ Vall,
    const float* __restrict__ KP2, const float* __restrict__ QM,
    const float* __restrict__ qtop, const float* __restrict__ qh0,
    float* __restrict__ out)
{
  const int b = blockIdx.x, tid = threadIdx.x;
  const int w = tid >> 6, lane = tid & 63;       // wave w = head w
  const int le = lane & 15, q4 = lane >> 4;      // 16-lane sub-groups

  __shared__ __align__(16) float kp2[32 * Sn * 4];   // 100 KB: k_ptr, [e/4][s][4]
  __shared__ __align__(16) float qv[En];
  __shared__ __align__(16) float octx[En];
  __shared__ float hqf[En];                      // qtop + first@Wq_bot (fixed after t=0)
  __shared__ float ctxs[En];
  __shared__ float uvals[256];
  __shared__ int   smask[256];
  __shared__ int   idx_s;
  __shared__ float logp_s;

  // ---- prologue: stage k_ptr to LDS ----
  {
    const float4* src = (const float4*)(KP2 + (size_t)b * (32 * Sn * 4));
    float4* dst = (float4*)kp2;
    for (int i = tid; i < 32 * Sn; i += 512) dst[i] = src[i];
  }
  // ---- K/V fragments: lane owns s in {lane, lane+64, lane+128, lane+192}, e-slice w*16.. ----
  float Kr[4][16], Vr[4][16];
#pragma unroll
  for (int j = 0; j < 4; ++j) {
    const int s = j * 64 + lane;
    if (s < Sn) {
      const float4* kq = (const float4*)(Kall + ((size_t)b * Sn + s) * En + w * DHn);
      const float4* vq = (const float4*)(Vall + ((size_t)b * Sn + s) * En + w * DHn);
#pragma unroll
      for (int q = 0; q < 4; ++q) {
        const float4 kv = kq[q], vv = vq[q];
        Kr[j][4*q+0] = kv.x; Kr[j][4*q+1] = kv.y; Kr[j][4*q+2] = kv.z; Kr[j][4*q+3] = kv.w;
        Vr[j][4*q+0] = vv.x; Vr[j][4*q+1] = vv.y; Vr[j][4*q+2] = vv.z; Vr[j][4*q+3] = vv.w;
      }
    } else {
#pragma unroll
      for (int d = 0; d < 16; ++d) { Kr[j][d] = 0.f; Vr[j][d] = 0.f; }
    }
  }
  // ---- Wo fragment: this lane's output col e = w*16+le, rows q4*32..q4*32+31 ----
  float WoR[32];
  {
    const float* wp = Wo + (size_t)(q4 * 32) * En + (w * DHn + le);
#pragma unroll
    for (int r = 0; r < 32; ++r) WoR[r] = wp[(size_t)r * En];
  }
  if (tid < 256) smask[tid] = (tid == 0) ? 1 : 0;     // depot masked from t=0
  if (tid < En)  qv[tid] = qh0[(size_t)b * En + tid]; // q at t=0 fully precomputed
  if (tid == 0) { logp_s = 0.f; out[SOL_OFF + (size_t)b * Sn] = 0.f; }
  __syncthreads();

  for (int t = 0; t < Tn; ++t) {
    // ---- scores + softmax + ctx, fully wave-local (head = wave) ----
    float qs[16];
    {
      const float4* qp = (const float4*)&qv[w * DHn];
#pragma unroll
      for (int q = 0; q < 4; ++q) {
        const float4 v = qp[q];
        qs[4*q+0] = v.x; qs[4*q+1] = v.y; qs[4*q+2] = v.z; qs[4*q+3] = v.w;
      }
    }
    float sc[4];
#pragma unroll
    for (int j = 0; j < 4; ++j) {
      const int s = j * 64 + lane;
      float a = 0.f;
#pragma unroll
      for (int d = 0; d < 16; ++d) a += qs[d] * Kr[j][d];
      sc[j] = (s >= Sn || smask[s]) ? NEG_INF : a * 0.25f;   // 1/sqrt(16)
    }
    float m = fmaxf(fmaxf(sc[0], sc[1]), fmaxf(sc[2], sc[3]));
#pragma unroll
    for (int off = 1; off < 64; off <<= 1) m = fmaxf(m, __shfl_xor(m, off));
    float ev[4]; float sum = 0.f;
#pragma unroll
    for (int j = 0; j < 4; ++j) { ev[j] = expf(sc[j] - m); sum += ev[j]; }
#pragma unroll
    for (int off = 1; off < 64; off <<= 1) sum += __shfl_xor(sum, off);
    const float inv = 1.f / sum;

    float acc[16];
#pragma unroll
    for (int d = 0; d < 16; ++d) acc[d] = 0.f;
#pragma unroll
    for (int j = 0; j < 4; ++j) {
      const float aj = ev[j] * inv;
#pragma unroll
      for (int d = 0; d < 16; ++d) acc[d] += aj * Vr[j][d];
    }
#pragma unroll
    for (int off = 1; off < 64; off <<= 1) {
#pragma unroll
      for (int d = 0; d < 16; ++d) acc[d] += __shfl_xor(acc[d], off);
    }
    if (lane == 0) {
#pragma unroll
      for (int d = 0; d < 16; ++d) ctxs[w * DHn + d] = acc[d];
    }
    __syncthreads();

    // ---- octx = ctx @ Wo (Wo in regs, ctx broadcast from LDS) ----
    {
      float p = 0.f;
      const float* cb = &ctxs[q4 * 32];
#pragma unroll
      for (int r = 0; r < 32; ++r) p += cb[r] * WoR[r];
      p += __shfl_xor(p, 16);
      p += __shfl_xor(p, 32);
      if (lane < 16) octx[w * DHn + le] = p;
    }
    __syncthreads();

    // ---- u[s] = tanh((octx . k_ptr[s]) / sqrt(128)) * 10; 2 threads per s ----
    {
      const int sp = tid >> 1, hf = tid & 1;
      float p = 0.f;
      if (sp < Sn) {
        const float4* oc = (const float4*)&octx[hf * 64];
#pragma unroll
        for (int e4 = 0; e4 < 16; ++e4)
          p += dot4(oc[e4], *(const float4*)&kp2[(((hf * 16 + e4) * Sn) + sp) << 2]);
      }
      p += __shfl_xor(p, 1);
      if (!hf) {
        if (sp < Sn) {
          const float uu = tanhf(p * 0.08838834764831845f) * 10.f;  // 1/sqrt(128)
          out[((size_t)b * Tn + t) * Sn + sp] = uu;                 // raw (unmasked) logits
          uvals[sp] = smask[sp] ? NEG_INF : uu;
        } else uvals[sp] = NEG_INF;
      }
    }
    __syncthreads();

    // ---- greedy argmax (first-index tie-break) + cross-entropy; wave 0 ----
    if (w == 0) {
      float bv = NEG_INF; int bi = 1 << 30;
#pragma unroll
      for (int k = 0; k < 4; ++k) {
        const int s = lane + 64 * k;
        const float v = uvals[s];
        if (v > bv || (v == bv && s < bi)) { bv = v; bi = s; }
      }
#pragma unroll
      for (int off = 1; off < 64; off <<= 1) {
        const float ovv = __shfl_xor(bv, off); const int oi = __shfl_xor(bi, off);
        if (ovv > bv || (ovv == bv && oi < bi)) { bv = ovv; bi = oi; }
      }
      float sum2 = 0.f;
#pragma unroll
      for (int k = 0; k < 4; ++k) sum2 += expf(uvals[lane + 64 * k] - bv); // exp(-inf)=0
#pragma unroll
      for (int off = 1; off < 64; off <<= 1) sum2 += __shfl_xor(sum2, off);
      if (lane == 0) {
        idx_s = bi;
        logp_s += logf(sum2);   // ce = log(sum(exp(u - max)))
        out[SOL_OFF + (size_t)b * Sn + t + 1] = (float)bi;
      }
    }
    __syncthreads();

    // ---- state update + next-step q ----
    const int idx = idx_s;
    if (tid == 0) smask[idx] = 1;

    if (t == 0) {
      // first = enc[b, idx0]: build hqf = qtop + first@Wq_bot (once)
      if (tid < En) uvals[tid] = enc[((size_t)b * Sn + idx) * En + tid];  // scratch
      __syncthreads();
      {
        float p = 0.f;
        const float* er  = &uvals[q4 * 32];
        const float* wqb = Wq + (size_t)(2 * En + q4 * 32) * En + (w * DHn + le);
#pragma unroll
        for (int r = 0; r < 32; ++r) p += er[r] * wqb[(size_t)r * En];
        p += __shfl_xor(p, 16);
        p += __shfl_xor(p, 32);
        if (lane < 16) hqf[w * DHn + le] = qtop[(size_t)b * En + (w * DHn + le)] + p;
      }
      __syncthreads();
    }

    if (t + 1 < Tn) {
      if (tid < En) qv[tid] = hqf[tid] + QM[((size_t)b * Sn + idx) * En + tid];
    }
    __syncthreads();
  }
  if (tid == 0) out[LOGP_OFF + b] = logp_s;
}

// ---------------------------------------------------------------------------
extern "C" void kernel_launch(void* const* d_in, const int* in_sizes, int n_in,
                              void* d_out, int out_size, void* d_ws, size_t ws_size,
                              hipStream_t stream)
{
  const float* enc = (const float*)d_in[0];
  // d_in[1] demands, d_in[2] capacities: unused by the forward pass
  const float* vl  = (const float*)d_in[3];
  const float* vf  = (const float*)d_in[4];
  const float* Wq  = (const float*)d_in[5];
  const float* Wk  = (const float*)d_in[6];
  const float* Wv  = (const float*)d_in[7];
  const float* Wo  = (const float*)d_in[8];
  const float* Wp  = (const float*)d_in[9];
  float* out = (float*)d_out;

  float* ws   = (float*)d_ws;
  const size_t BSE = (size_t)Bn * Sn * En;
  float* Kall = ws;                 // [B][S][E]
  float* Vall = Kall + BSE;         // [B][S][E]
  float* QM   = Vall + BSE;         // [B][S][E]  enc@Wq_mid
  float* KP2  = QM   + BSE;         // [B][32][S][4]  enc@Wp, e-grouped
  float* qtop = KP2  + BSE;         // [B][E]
  float* qh0  = qtop + (size_t)Bn * En;  // [B][E]

  hipLaunchKernelGGL(hhat_kernel, dim3(Bn), dim3(En), 0, stream, enc, vl, vf, Wq, qtop, qh0);
  hipLaunchKernelGGL(proj_kernel, dim3((Bn * Sn) / 32), dim3(256), 0, stream,
                     enc, Wk, Wv, Wq, Wp, Kall, Vall, QM, KP2);
  hipLaunchKernelGGL(decode_kernel, dim3(Bn), dim3(512), 0, stream,
                     enc, Wq, Wo, Kall, Vall, KP2, QM, qtop, qh0, out);
}